// Round 8
// baseline (103.881 us; speedup 1.0000x reference)
//
#include <hip/hip_runtime.h>
#include <hip/hip_bf16.h>

typedef unsigned short u16;
typedef __attribute__((ext_vector_type(8))) __bf16 bf16x8;
typedef __attribute__((ext_vector_type(4))) float f32x4;

#define B_SZ 4096
#define D_SZ 1024
#define MARGIN 0.2f

__device__ __forceinline__ u16 f2bf(float x) {
  __hip_bfloat16 h = __float2bfloat16(x);
  u16 r; __builtin_memcpy(&r, &h, 2); return r;
}

// ---------------- normalize + cast to bf16 + diag ----------------
__global__ void norm_diag_kernel(const float* __restrict__ im,
                                 const float* __restrict__ tx,
                                 u16* __restrict__ imn,
                                 u16* __restrict__ txn,
                                 float* __restrict__ diag) {
  const int row = blockIdx.x;
  const int t = threadIdx.x;
  const size_t base = (size_t)row * D_SZ;
  float4 vi = reinterpret_cast<const float4*>(im + base)[t];
  float4 vt = reinterpret_cast<const float4*>(tx + base)[t];
  float ssi = vi.x * vi.x + vi.y * vi.y + vi.z * vi.z + vi.w * vi.w;
  float sst = vt.x * vt.x + vt.y * vt.y + vt.z * vt.z + vt.w * vt.w;
  float dot = vi.x * vt.x + vi.y * vt.y + vi.z * vt.z + vi.w * vt.w;
#pragma unroll
  for (int off = 32; off > 0; off >>= 1) {
    ssi += __shfl_down(ssi, off, 64);
    sst += __shfl_down(sst, off, 64);
    dot += __shfl_down(dot, off, 64);
  }
  __shared__ float w[3][4];
  if ((t & 63) == 0) { int wi = t >> 6; w[0][wi] = ssi; w[1][wi] = sst; w[2][wi] = dot; }
  __syncthreads();
  const float tssi = (w[0][0] + w[0][1]) + (w[0][2] + w[0][3]);
  const float tsst = (w[1][0] + w[1][1]) + (w[1][2] + w[1][3]);
  const float tdot = (w[2][0] + w[2][1]) + (w[2][2] + w[2][3]);
  const float si = 1.0f / fmaxf(sqrtf(tssi), 1e-12f);
  const float st = 1.0f / fmaxf(sqrtf(tsst), 1e-12f);
  u16 oi[4] = { f2bf(vi.x * si), f2bf(vi.y * si), f2bf(vi.z * si), f2bf(vi.w * si) };
  u16 ot[4] = { f2bf(vt.x * st), f2bf(vt.y * st), f2bf(vt.z * st), f2bf(vt.w * st) };
  ushort4 pi, pt; __builtin_memcpy(&pi, oi, 8); __builtin_memcpy(&pt, ot, 8);
  reinterpret_cast<ushort4*>(imn + base)[t] = pi;
  reinterpret_cast<ushort4*>(txn + base)[t] = pt;
  if (t == 0) diag[row] = tdot * si * st;
}

// ---------------- 128x128 / BK=64 multi-block-per-CU GEMM + fused loss ------
// Round-8: trade schedule depth for block-level TLP (m97/m114 mechanism).
// 256 threads (4 waves, 2x2, 64x64 per wave), 32 KiB single-buffered LDS
// -> ~3 blocks resident per CU; co-resident blocks hide the sync drains and
// each other's epilogue writes. m97-exact sync structure (stage; sync;
// read+MFMA; sync) with NO inline waits - compiler schedules lgkm.
// LDS: A,B regions [128 rows][64 cols] (128B pitch) with the r6-proven
// zero-conflict XOR involution (stored slot = nominal ^ (row&7)), staged via
// pre-swizzled global source, linear gload_lds dest (rule #21).
__device__ __forceinline__ void gload_lds16(const u16* g, u16* l) {
  __builtin_amdgcn_global_load_lds((__attribute__((address_space(1))) void*)g,
                                   (__attribute__((address_space(3))) void*)l,
                                   16, 0, 0);
}

__global__ __launch_bounds__(256, 3) void gemm_loss_kernel(
    const u16* __restrict__ A,   // imn [4096][1024]
    const u16* __restrict__ Bt,  // txn [4096][1024]
    const float* __restrict__ diag,
    float* __restrict__ sim,     // d_out+1, row-major [4096][4096]
    float* __restrict__ loss) {
  __shared__ u16 As[8192];       // [128][64] u16, 16 KiB
  __shared__ u16 Bs[8192];

  const int tid = threadIdx.x;
  const int l = tid & 63;
  const int w = tid >> 6;        // wave 0..3
  const int wr = w >> 1, wc = w & 1;
  const int ar = l & 15;
  const int arh = l >> 4;

  // XCD-aware bijective swizzle: 1024 blocks, 8 XCDs, 128 consecutive per XCD.
  const int bid = blockIdx.x;
  const int s = (bid & 7) * 128 + (bid >> 3);
  const int tm = (s >> 5) * 128;
  const int tn = (s & 31) * 128;

  f32x4 acc[4][4] = {};

  // ---- staging (pre-swizzled global source; linear LDS dest) ----
  const int rb = tid >> 3;                   // 0..31: row within 32-row chunk
  const int cbb = (tid & 7) ^ (rb & 7);      // involution with read swizzle
  const u16* gA = A + (size_t)(tm + rb) * D_SZ + cbb * 8;
  const u16* gB = Bt + (size_t)(tn + rb) * D_SZ + cbb * 8;
  u16* ldA = As + w * 512;                   // wave-uniform dest
  u16* ldB = Bs + w * 512;

  // ---- read offsets (stored slot = (ks*4+arh) ^ (row&7); row&7 == ar&7) ----
  const int sl0 = (arh ^ (ar & 7)) * 8;
  const int sl1 = ((4 + arh) ^ (ar & 7)) * 8;
  const int aOfs = (wr * 64 + ar) * 64;
  const int bOfs = (wc * 64 + ar) * 64;

#pragma unroll 1
  for (int t = 0; t < 16; ++t) {
    const int k0 = t * 64;
#pragma unroll
    for (int c = 0; c < 4; c++) {            // 8 gload_lds: 32 KiB total
      gload_lds16(gA + (size_t)c * 32 * D_SZ + k0, ldA + c * 2048);
      gload_lds16(gB + (size_t)c * 32 * D_SZ + k0, ldB + c * 2048);
    }
    __syncthreads();                         // drain; co-resident blocks hide
    bf16x8 a[4][2], b[4][2];
#pragma unroll
    for (int m = 0; m < 4; m++) {
      const u16* p = As + aOfs + m * 16 * 64;
      a[m][0] = *(const bf16x8*)&p[sl0];
      a[m][1] = *(const bf16x8*)&p[sl1];
    }
#pragma unroll
    for (int n = 0; n < 4; n++) {
      const u16* p = Bs + bOfs + n * 16 * 64;
      b[n][0] = *(const bf16x8*)&p[sl0];
      b[n][1] = *(const bf16x8*)&p[sl1];
    }
#pragma unroll
    for (int m = 0; m < 4; m++)
#pragma unroll
      for (int n = 0; n < 4; n++) {
        acc[m][n] = __builtin_amdgcn_mfma_f32_16x16x32_bf16(a[m][0], b[n][0], acc[m][n], 0, 0, 0);
        acc[m][n] = __builtin_amdgcn_mfma_f32_16x16x32_bf16(a[m][1], b[n][1], acc[m][n], 0, 0, 0);
      }
    __syncthreads();                         // protect LDS before next stage
  }

  // ---- C-write + hinge loss ----
  float dcs[4];
#pragma unroll
  for (int n = 0; n < 4; n++) dcs[n] = diag[tn + wc * 64 + n * 16 + ar];
  float lsum = 0.f;
#pragma unroll
  for (int m = 0; m < 4; m++) {
#pragma unroll
    for (int i = 0; i < 4; i++) {
      const int r = tm + wr * 64 + m * 16 + arh * 4 + i;
      const float dr = diag[r];
#pragma unroll
      for (int n = 0; n < 4; n++) {
        const int c = tn + wc * 64 + n * 16 + ar;
        const float s_ = acc[m][n][i];
        sim[(size_t)r * B_SZ + c] = s_;
        if (r != c)
          lsum += fmaxf(MARGIN + s_ - dr, 0.f) + fmaxf(MARGIN + s_ - dcs[n], 0.f);
      }
    }
  }
#pragma unroll
  for (int off = 32; off > 0; off >>= 1) lsum += __shfl_down(lsum, off, 64);
  if (l == 0) atomicAdd(loss, lsum);
}

extern "C" void kernel_launch(void* const* d_in, const int* in_sizes, int n_in,
                              void* d_out, int out_size, void* d_ws, size_t ws_size,
                              hipStream_t stream) {
  const float* im = (const float*)d_in[0];
  const float* tx = (const float*)d_in[1];
  float* out = (float*)d_out;
  float* loss = out;        // output 0: scalar total_loss
  float* sim = out + 1;     // output 1: [4096][4096]

  u16* imn = (u16*)d_ws;
  u16* txn = imn + (size_t)B_SZ * D_SZ;
  float* diag = (float*)(txn + (size_t)B_SZ * D_SZ);

  hipMemsetAsync(d_out, 0, sizeof(float), stream);
  norm_diag_kernel<<<B_SZ, 256, 0, stream>>>(im, tx, imn, txn, diag);
  gemm_loss_kernel<<<(B_SZ / 128) * (B_SZ / 128), 256, 0, stream>>>(imn, txn, diag, sim, loss);
}

// Round 10
// 90.416 us; speedup vs baseline: 1.1489x; 1.1489x over previous
//
#include <hip/hip_runtime.h>
#include <hip/hip_bf16.h>

typedef unsigned short u16;
typedef __attribute__((ext_vector_type(8))) __bf16 bf16x8;
typedef __attribute__((ext_vector_type(4))) float f32x4;

#define B_SZ 4096
#define D_SZ 1024
#define MARGIN 0.2f

__device__ __forceinline__ u16 f2bf(float x) {
  __hip_bfloat16 h = __float2bfloat16(x);
  u16 r; __builtin_memcpy(&r, &h, 2); return r;
}

// ---------------- normalize + cast to bf16 + diag ----------------
__global__ void norm_diag_kernel(const float* __restrict__ im,
                                 const float* __restrict__ tx,
                                 u16* __restrict__ imn,
                                 u16* __restrict__ txn,
                                 float* __restrict__ diag) {
  const int row = blockIdx.x;
  const int t = threadIdx.x;
  const size_t base = (size_t)row * D_SZ;
  float4 vi = reinterpret_cast<const float4*>(im + base)[t];
  float4 vt = reinterpret_cast<const float4*>(tx + base)[t];
  float ssi = vi.x * vi.x + vi.y * vi.y + vi.z * vi.z + vi.w * vi.w;
  float sst = vt.x * vt.x + vt.y * vt.y + vt.z * vt.z + vt.w * vt.w;
  float dot = vi.x * vt.x + vi.y * vt.y + vi.z * vt.z + vi.w * vt.w;
#pragma unroll
  for (int off = 32; off > 0; off >>= 1) {
    ssi += __shfl_down(ssi, off, 64);
    sst += __shfl_down(sst, off, 64);
    dot += __shfl_down(dot, off, 64);
  }
  __shared__ float w[3][4];
  if ((t & 63) == 0) { int wi = t >> 6; w[0][wi] = ssi; w[1][wi] = sst; w[2][wi] = dot; }
  __syncthreads();
  const float tssi = (w[0][0] + w[0][1]) + (w[0][2] + w[0][3]);
  const float tsst = (w[1][0] + w[1][1]) + (w[1][2] + w[1][3]);
  const float tdot = (w[2][0] + w[2][1]) + (w[2][2] + w[2][3]);
  const float si = 1.0f / fmaxf(sqrtf(tssi), 1e-12f);
  const float st = 1.0f / fmaxf(sqrtf(tsst), 1e-12f);
  u16 oi[4] = { f2bf(vi.x * si), f2bf(vi.y * si), f2bf(vi.z * si), f2bf(vi.w * si) };
  u16 ot[4] = { f2bf(vt.x * st), f2bf(vt.y * st), f2bf(vt.z * st), f2bf(vt.w * st) };
  ushort4 pi, pt; __builtin_memcpy(&pi, oi, 8); __builtin_memcpy(&pt, ot, 8);
  reinterpret_cast<ushort4*>(imn + base)[t] = pi;
  reinterpret_cast<ushort4*>(txn + base)[t] = pt;
  if (t == 0) diag[row] = tdot * si * st;
}

// ---------------- 256x256 GEMM, 1024 threads / 16 waves, BK=64 -------------
// Round-10: r9 design with the missing PROLOGUE STAGE fixed (r9 read buf0 at
// t=0 without ever staging it -> inf). 16 waves as 4M x 4N (64x64 per wave);
// register budget <=128/wave forced by __launch_bounds__(1024,4) so the whole
// 16-wave block is resident (4 waves/SIMD). Loss in a separate kernel; GEMM
// epilogue is pure stores. One barrier per K-tile, double-buffered LDS.
// LDS: 2 bufs x 4 regions [A0,A1,B0,B1] of [128 rows][64 u16] (128B pitch),
// zero-conflict XOR involution (r6-proven), staged via pre-swizzled global
// source with linear gload_lds dest (rule #21).
__device__ __forceinline__ void gload_lds16(const u16* g, u16* l) {
  __builtin_amdgcn_global_load_lds((__attribute__((address_space(1))) void*)g,
                                   (__attribute__((address_space(3))) void*)l,
                                   16, 0, 0);
}

__global__ __launch_bounds__(1024, 4) void gemm_kernel(
    const u16* __restrict__ A,   // imn [4096][1024]
    const u16* __restrict__ Bt,  // txn [4096][1024]
    float* __restrict__ sim) {   // d_out+1, row-major [4096][4096]
  __shared__ u16 sm[65536];      // 2 bufs x 4 regions x 8192 u16 = 128 KiB

  const int tid = threadIdx.x;
  const int l = tid & 63;
  const int w = tid >> 6;        // wave 0..15
  const int wr = w >> 2;         // 0..3  M quarter
  const int wc = w & 3;          // 0..3  N quarter
  const int ar = l & 15;
  const int arh = l >> 4;

  // XCD-aware bijective swizzle: 256 blocks, 8 XCDs, 32 consecutive per XCD.
  const int bid = blockIdx.x;
  const int s = (bid & 7) * 32 + (bid >> 3);
  const int tm = (s >> 4) * 256;
  const int tn = (s & 15) * 256;

  f32x4 acc[4][4] = {};

  // ---- staging: wave w stages rows 8w..8w+8 of each region ----
  const int l3 = l >> 3;
  const int cb = (l & 7) ^ l3;             // involution with read swizzle
  const int rho = w * 8 + l3;              // 0..127
  const u16* pR[4];
  pR[0] = A  + (size_t)(tm + rho)       * D_SZ + cb * 8;   // A0
  pR[1] = A  + (size_t)(tm + 128 + rho) * D_SZ + cb * 8;   // A1
  pR[2] = Bt + (size_t)(tn + rho)       * D_SZ + cb * 8;   // B0
  pR[3] = Bt + (size_t)(tn + 128 + rho) * D_SZ + cb * 8;   // B1

  // ---- read offsets (stored slot = (ks*4+arh) ^ (row&7); row&7 == ar&7) ----
  const int sl0 = (arh ^ (ar & 7)) * 8;
  const int sl1 = ((4 + arh) ^ (ar & 7)) * 8;
  const int aOfs = ((wr & 1) * 64 + ar) * 64;   // within region A(wr>>1)
  const int bOfs = ((wc & 1) * 64 + ar) * 64;   // within region B(wc>>1)
  const int aReg = wr >> 1;                     // 0..1
  const int bReg = 2 + (wc >> 1);               // 2..3

  // ---- PROLOGUE: stage K-tile 0 into buf 0 (this was missing in r9) ----
#pragma unroll
  for (int c = 0; c < 4; c++)
    gload_lds16(pR[c], sm + c * 8192 + w * 512);
  __syncthreads();

#pragma unroll 1
  for (int t = 0; t < 16; ++t) {
    const int buf = t & 1;
    if (t + 1 < 16) {
      const int nb = buf ^ 1;
      const int ko = (t + 1) * 64;
#pragma unroll
      for (int c = 0; c < 4; c++)
        gload_lds16(pR[c] + ko, sm + (nb * 4 + c) * 8192 + w * 512);
    }
    const u16* Ab = sm + (buf * 4 + aReg) * 8192 + aOfs;
    const u16* Bb = sm + (buf * 4 + bReg) * 8192 + bOfs;
    {
      bf16x8 af[4], bfr[4];
#pragma unroll
      for (int m = 0; m < 4; m++) af[m] = *(const bf16x8*)&Ab[m * 1024 + sl0];
#pragma unroll
      for (int n = 0; n < 4; n++) bfr[n] = *(const bf16x8*)&Bb[n * 1024 + sl0];
#pragma unroll
      for (int m = 0; m < 4; m++)
#pragma unroll
        for (int n = 0; n < 4; n++)
          acc[m][n] = __builtin_amdgcn_mfma_f32_16x16x32_bf16(af[m], bfr[n], acc[m][n], 0, 0, 0);
    }
    {
      bf16x8 af[4], bfr[4];
#pragma unroll
      for (int m = 0; m < 4; m++) af[m] = *(const bf16x8*)&Ab[m * 1024 + sl1];
#pragma unroll
      for (int n = 0; n < 4; n++) bfr[n] = *(const bf16x8*)&Bb[n * 1024 + sl1];
#pragma unroll
      for (int m = 0; m < 4; m++)
#pragma unroll
        for (int n = 0; n < 4; n++)
          acc[m][n] = __builtin_amdgcn_mfma_f32_16x16x32_bf16(af[m], bfr[n], acc[m][n], 0, 0, 0);
    }
    __syncthreads();   // drains stage(t+1) + protects buf for stage(t+2)
  }

  // ---- epilogue: pure sim stores ----
#pragma unroll
  for (int m = 0; m < 4; m++) {
#pragma unroll
    for (int i = 0; i < 4; i++) {
      const int r = tm + wr * 64 + m * 16 + arh * 4 + i;
#pragma unroll
      for (int n = 0; n < 4; n++) {
        const int c = tn + wc * 64 + n * 16 + ar;
        sim[(size_t)r * B_SZ + c] = acc[m][n][i];
      }
    }
  }
}

// ---------------- hinge loss over sim (LLC-hot re-read) ----------------
__global__ __launch_bounds__(256) void loss_kernel(
    const float* __restrict__ sim,
    const float* __restrict__ diag,
    float* __restrict__ loss) {
  const int nthreads = gridDim.x * 256;
  const int gtid = blockIdx.x * 256 + threadIdx.x;
  float lsum = 0.f;
  for (int q = gtid; q < (B_SZ * B_SZ / 4); q += nthreads) {
    const int lin = q * 4;
    const int r = lin >> 12;
    const int cbase = lin & (B_SZ - 1);
    const float4 s4 = reinterpret_cast<const float4*>(sim)[q];
    const float dr = diag[r];
    const float4 dc = reinterpret_cast<const float4*>(diag)[cbase >> 2];
    const float ss[4] = { s4.x, s4.y, s4.z, s4.w };
    const float dd[4] = { dc.x, dc.y, dc.z, dc.w };
#pragma unroll
    for (int j = 0; j < 4; j++) {
      if (r != cbase + j)
        lsum += fmaxf(MARGIN + ss[j] - dr, 0.f) + fmaxf(MARGIN + ss[j] - dd[j], 0.f);
    }
  }
#pragma unroll
  for (int off = 32; off > 0; off >>= 1) lsum += __shfl_down(lsum, off, 64);
  __shared__ float wsum[4];
  if ((threadIdx.x & 63) == 0) wsum[threadIdx.x >> 6] = lsum;
  __syncthreads();
  if (threadIdx.x == 0)
    atomicAdd(loss, (wsum[0] + wsum[1]) + (wsum[2] + wsum[3]));
}

extern "C" void kernel_launch(void* const* d_in, const int* in_sizes, int n_in,
                              void* d_out, int out_size, void* d_ws, size_t ws_size,
                              hipStream_t stream) {
  const float* im = (const float*)d_in[0];
  const float* tx = (const float*)d_in[1];
  float* out = (float*)d_out;
  float* loss = out;        // output 0: scalar total_loss
  float* sim = out + 1;     // output 1: [4096][4096]

  u16* imn = (u16*)d_ws;
  u16* txn = imn + (size_t)B_SZ * D_SZ;
  float* diag = (float*)(txn + (size_t)B_SZ * D_SZ);

  hipMemsetAsync(d_out, 0, sizeof(float), stream);
  norm_diag_kernel<<<B_SZ, 256, 0, stream>>>(im, tx, imn, txn, diag);
  gemm_kernel<<<(B_SZ / 256) * (B_SZ / 256), 1024, 0, stream>>>(imn, txn, sim);
  loss_kernel<<<2048, 256, 0, stream>>>(sim, diag, loss);
}